// Round 1
// baseline (346.944 us; speedup 1.0000x reference)
//
#include <hip/hip_runtime.h>

// ---------------------------------------------------------------------------
// ElementwiseTensorProducts: fused bf16-MFMA kernel.
// B=16,N=4096 -> 65536 tokens, CHAN=128, RANK=64.
// Per WG: 16 tokens. Phases:
//  1) stage z0(16x128)+z1(48x128) fp32->bf16 into LDS (XOR swizzle)
//  2) projections z0_l/z0_r/z1_l/z1_r via mfma 16x16x32 bf16, +bias, ->LDS
//  3) elementwise products p00,p110,q011,q101,q111 -> P0[16][128],P1[48][192] LDS
//  4) output GEMMs (W0o 128x128, W1o 128x192) + b0o, store fp32
// ---------------------------------------------------------------------------

typedef float  f32x4  __attribute__((ext_vector_type(4)));
typedef __bf16 bf16x8 __attribute__((ext_vector_type(8)));

#define TOK 16
// LDS byte layout:
// region1 [0,22528): Ain 64 rows x 256B (phases 1-2); then P0 16x256B @0, P1 48x384B @4096 (phases 3-4)
// region2 [22528,38912): proj bf16 buffers
#define P1_BASE 4096
#define PRJ_Z0L 22528
#define PRJ_Z0R 24576
#define PRJ_Z1L 26624
#define PRJ_Z1R 32768
#define LDS_BYTES 38912

__device__ __forceinline__ unsigned packbf(float lo, float hi) {
    unsigned a = (unsigned)__builtin_bit_cast(unsigned short, (__bf16)lo);
    unsigned b = (unsigned)__builtin_bit_cast(unsigned short, (__bf16)hi);
    return a | (b << 16);
}
__device__ __forceinline__ float bflo(unsigned u) { return __builtin_bit_cast(float, u << 16); }
__device__ __forceinline__ float bfhi(unsigned u) { return __builtin_bit_cast(float, u & 0xffff0000u); }
__device__ __forceinline__ void st_bf(void* p, float v) {
    *(unsigned short*)p = __builtin_bit_cast(unsigned short, (__bf16)v);
}
// load 8 consecutive fp32 -> bf16x8 fragment (weights are [N][K] row-major = exactly B-frag layout)
__device__ __forceinline__ bf16x8 cvtW(const float* p) {
    float4 a = *(const float4*)p;
    float4 b = *(const float4*)(p + 4);
    bf16x8 r;
    r[0] = (__bf16)a.x; r[1] = (__bf16)a.y; r[2] = (__bf16)a.z; r[3] = (__bf16)a.w;
    r[4] = (__bf16)b.x; r[5] = (__bf16)b.y; r[6] = (__bf16)b.z; r[7] = (__bf16)b.w;
    return r;
}
__device__ __forceinline__ f32x4 mm(bf16x8 a, bf16x8 b, f32x4 c) {
    return __builtin_amdgcn_mfma_f32_16x16x32_bf16(a, b, c, 0, 0, 0);
}

__global__ __launch_bounds__(256, 2)
void etp_kernel(const float* __restrict__ z0, const float* __restrict__ z1,
                const float* __restrict__ W0l, const float* __restrict__ b0l,
                const float* __restrict__ W0r, const float* __restrict__ b0r,
                const float* __restrict__ W1l, const float* __restrict__ W1r,
                const float* __restrict__ W0o, const float* __restrict__ b0o,
                const float* __restrict__ W1o,
                float* __restrict__ out0, float* __restrict__ out1)
{
    __shared__ __align__(16) unsigned char smem[LDS_BYTES];
    const int tid = threadIdx.x;
    const int m0  = blockIdx.x * TOK;

    // ---------------- phase 1: stage inputs to LDS as bf16 (swizzled) -------
    {
        const float4* z0v = (const float4*)(z0 + (size_t)m0 * 128);       // 16 rows x 32 f4
        const float4* z1v = (const float4*)(z1 + (size_t)m0 * 3 * 128);   // 48 rows x 32 f4
        #pragma unroll
        for (int it = 0; it < 2; ++it) {
            int idx = tid + it * 256;               // [0,512)
            int row = idx >> 5, c4 = idx & 31;
            float4 v = z0v[idx];
            *(uint2*)(smem + row * 256 + ((c4 * 8) ^ ((row & 7) << 4))) =
                make_uint2(packbf(v.x, v.y), packbf(v.z, v.w));
        }
        #pragma unroll
        for (int it = 0; it < 6; ++it) {
            int idx = tid + it * 256;               // [0,1536)
            int row = 16 + (idx >> 5), c4 = idx & 31;
            float4 v = z1v[idx];
            *(uint2*)(smem + row * 256 + ((c4 * 8) ^ ((row & 7) << 4))) =
                make_uint2(packbf(v.x, v.y), packbf(v.z, v.w));
        }
    }
    __syncthreads();

    const int l  = tid & 63;
    const int w  = tid >> 6;
    const int lr = l & 15;    // row-in-tile for A, n-row for B, col for C
    const int lg = l >> 4;    // 16-lane group

    // ---------------- phase 2: projections ----------------------------------
    {
        const int r0 = w * 16;                      // this wave's rank n-tile
        bf16x8 bL0[4], bR0[4], bL1[4], bR1[4];
        #pragma unroll
        for (int k = 0; k < 4; ++k) {
            const int off  = k * 32 + lg * 8;
            const int wrow = (r0 + lr) * 128 + off;
            bL0[k] = cvtW(W0l + wrow);
            bR0[k] = cvtW(W0r + wrow);
            bL1[k] = cvtW(W1l + wrow);
            bR1[k] = cvtW(W1r + wrow);
        }
        f32x4 zero = {0.f, 0.f, 0.f, 0.f};
        f32x4 accL0 = zero, accR0 = zero;
        f32x4 accL1[3], accR1[3];
        #pragma unroll
        for (int mt = 0; mt < 3; ++mt) { accL1[mt] = zero; accR1[mt] = zero; }

        { // z0 rows 0..15
            bf16x8 a[4];
            #pragma unroll
            for (int k = 0; k < 4; ++k)
                a[k] = *(const bf16x8*)(smem + lr * 256 + ((k * 64 + lg * 16) ^ ((lr & 7) << 4)));
            #pragma unroll
            for (int k = 0; k < 4; ++k) {
                accL0 = mm(a[k], bL0[k], accL0);
                accR0 = mm(a[k], bR0[k], accR0);
            }
        }
        #pragma unroll
        for (int mt = 0; mt < 3; ++mt) { // z1 rows 16..63
            const int arow = 16 + mt * 16 + lr;
            bf16x8 a[4];
            #pragma unroll
            for (int k = 0; k < 4; ++k)
                a[k] = *(const bf16x8*)(smem + arow * 256 + ((k * 64 + lg * 16) ^ ((arow & 7) << 4)));
            #pragma unroll
            for (int k = 0; k < 4; ++k) {
                accL1[mt] = mm(a[k], bL1[k], accL1[mt]);
                accR1[mt] = mm(a[k], bR1[k], accR1[mt]);
            }
        }
        // write projections (bf16) + biases for the z0 pair
        const float bl = b0l[r0 + lr], br = b0r[r0 + lr];
        const int   cb = (r0 + lr) * 2;
        #pragma unroll
        for (int j = 0; j < 4; ++j) {
            const int trow = lg * 4 + j, sw = (trow & 7) << 4;
            st_bf(smem + PRJ_Z0L + trow * 128 + (cb ^ sw), accL0[j] + bl);
            st_bf(smem + PRJ_Z0R + trow * 128 + (cb ^ sw), accR0[j] + br);
        }
        #pragma unroll
        for (int mt = 0; mt < 3; ++mt)
            #pragma unroll
            for (int j = 0; j < 4; ++j) {
                const int zr = mt * 16 + lg * 4 + j, sw = (zr & 7) << 4;
                st_bf(smem + PRJ_Z1L + zr * 128 + (cb ^ sw), accL1[mt][j]);
                st_bf(smem + PRJ_Z1R + zr * 128 + (cb ^ sw), accR1[mt][j]);
            }
    }
    __syncthreads();   // proj ready; Ain region now dead -> safe to write P

    // ---------------- phase 3: elementwise products -> P0/P1 ----------------
    {
        #pragma unroll
        for (int it = 0; it < 2; ++it) {            // P0: 16 rows x 32 col-pairs
            const int e = tid + it * 256;
            const int t = e >> 5, cb4 = (e & 31) * 4;
            const int swt = (t & 7) << 4;
            unsigned ul = *(const unsigned*)(smem + PRJ_Z0L + t * 128 + (cb4 ^ swt));
            unsigned ur = *(const unsigned*)(smem + PRJ_Z0R + t * 128 + (cb4 ^ swt));
            float p0 = bflo(ul) * bflo(ur), p1 = bfhi(ul) * bfhi(ur);
            float s0 = 0.f, s1 = 0.f;
            #pragma unroll
            for (int i = 0; i < 3; ++i) {
                const int zr = 3 * t + i, sw = (zr & 7) << 4;
                unsigned al = *(const unsigned*)(smem + PRJ_Z1L + zr * 128 + (cb4 ^ sw));
                unsigned ar = *(const unsigned*)(smem + PRJ_Z1R + zr * 128 + (cb4 ^ sw));
                s0 += bflo(al) * bflo(ar);
                s1 += bfhi(al) * bfhi(ar);
            }
            *(unsigned*)(smem + t * 256 + (cb4 ^ swt))         = packbf(p0, p1);
            *(unsigned*)(smem + t * 256 + ((128 + cb4) ^ swt)) = packbf(s0, s1);
        }
        #pragma unroll
        for (int it = 0; it < 6; ++it) {            // P1: 48 rows x 32 col-pairs
            const int e = tid + it * 256;
            const int row = e >> 5, cb4 = (e & 31) * 4;
            const int t = row / 3, i = row - 3 * t;
            const int i1 = (i == 2) ? 0 : i + 1;
            const int i2 = (i == 0) ? 2 : i - 1;
            const int swr = (row & 7) << 4, swt = (t & 7) << 4;
            unsigned u1l = *(const unsigned*)(smem + PRJ_Z1L + row * 128 + (cb4 ^ swr));
            unsigned u1r = *(const unsigned*)(smem + PRJ_Z1R + row * 128 + (cb4 ^ swr));
            unsigned u0l = *(const unsigned*)(smem + PRJ_Z0L + t * 128 + (cb4 ^ swt));
            unsigned u0r = *(const unsigned*)(smem + PRJ_Z0R + t * 128 + (cb4 ^ swt));
            const int ra = 3 * t + i1, rb = 3 * t + i2;
            unsigned la  = *(const unsigned*)(smem + PRJ_Z1L + ra * 128 + (cb4 ^ ((ra & 7) << 4)));
            unsigned rbv = *(const unsigned*)(smem + PRJ_Z1R + rb * 128 + (cb4 ^ ((rb & 7) << 4)));
            unsigned lb  = *(const unsigned*)(smem + PRJ_Z1L + rb * 128 + (cb4 ^ ((rb & 7) << 4)));
            unsigned rav = *(const unsigned*)(smem + PRJ_Z1R + ra * 128 + (cb4 ^ ((ra & 7) << 4)));
            float q01_0 = bflo(u0l) * bflo(u1r), q01_1 = bfhi(u0l) * bfhi(u1r);
            float q10_0 = bflo(u1l) * bflo(u0r), q10_1 = bfhi(u1l) * bfhi(u0r);
            float q11_0 = bflo(la) * bflo(rbv) - bflo(lb) * bflo(rav);
            float q11_1 = bfhi(la) * bfhi(rbv) - bfhi(lb) * bfhi(rav);
            unsigned char* base = smem + P1_BASE + row * 384;
            *(unsigned*)(base + (cb4 ^ swr))         = packbf(q01_0, q01_1);
            *(unsigned*)(base + ((128 + cb4) ^ swr)) = packbf(q10_0, q10_1);
            *(unsigned*)(base + ((256 + cb4) ^ swr)) = packbf(q11_0, q11_1);
        }
    }
    __syncthreads();

    // ---------------- phase 4: output GEMMs + store --------------------------
    {
        bf16x8 bO0[2][4], bO1[2][6];
        #pragma unroll
        for (int nn = 0; nn < 2; ++nn) {
            const int crow = nn * 64 + w * 16 + lr;
            #pragma unroll
            for (int k = 0; k < 4; ++k) bO0[nn][k] = cvtW(W0o + crow * 128 + k * 32 + lg * 8);
            #pragma unroll
            for (int k = 0; k < 6; ++k) bO1[nn][k] = cvtW(W1o + crow * 192 + k * 32 + lg * 8);
        }
        f32x4 zero = {0.f, 0.f, 0.f, 0.f};
        f32x4 o0[2]; f32x4 o1[2][3];
        #pragma unroll
        for (int nn = 0; nn < 2; ++nn) {
            o0[nn] = zero;
            #pragma unroll
            for (int mt = 0; mt < 3; ++mt) o1[nn][mt] = zero;
        }
        { // out0 from P0
            bf16x8 a[4];
            #pragma unroll
            for (int k = 0; k < 4; ++k)
                a[k] = *(const bf16x8*)(smem + lr * 256 + ((k * 64 + lg * 16) ^ ((lr & 7) << 4)));
            #pragma unroll
            for (int nn = 0; nn < 2; ++nn)
                #pragma unroll
                for (int k = 0; k < 4; ++k) o0[nn] = mm(a[k], bO0[nn][k], o0[nn]);
        }
        #pragma unroll
        for (int mt = 0; mt < 3; ++mt) { // out1 from P1
            const int arow = mt * 16 + lr;
            bf16x8 a[6];
            #pragma unroll
            for (int k = 0; k < 6; ++k)
                a[k] = *(const bf16x8*)(smem + P1_BASE + arow * 384 + ((k * 64 + lg * 16) ^ ((arow & 7) << 4)));
            #pragma unroll
            for (int nn = 0; nn < 2; ++nn)
                #pragma unroll
                for (int k = 0; k < 6; ++k) o1[nn][mt] = mm(a[k], bO1[nn][k], o1[nn][mt]);
        }
        // stores
        #pragma unroll
        for (int nn = 0; nn < 2; ++nn) {
            const int c = nn * 64 + w * 16 + lr;
            const float bias = b0o[c];
            #pragma unroll
            for (int j = 0; j < 4; ++j) {
                const int t = lg * 4 + j;
                out0[(size_t)(m0 + t) * 128 + c] = o0[nn][j] + bias;
            }
            #pragma unroll
            for (int mt = 0; mt < 3; ++mt)
                #pragma unroll
                for (int j = 0; j < 4; ++j) {
                    const int zr = mt * 16 + lg * 4 + j;
                    out1[((size_t)m0 * 3 + zr) * 128 + c] = o1[nn][mt][j];
                }
        }
    }
}

extern "C" void kernel_launch(void* const* d_in, const int* in_sizes, int n_in,
                              void* d_out, int out_size, void* d_ws, size_t ws_size,
                              hipStream_t stream)
{
    const float* z0  = (const float*)d_in[0];
    const float* z1  = (const float*)d_in[1];
    const float* W0l = (const float*)d_in[2];
    const float* b0l = (const float*)d_in[3];
    const float* W0r = (const float*)d_in[4];
    const float* b0r = (const float*)d_in[5];
    const float* W1l = (const float*)d_in[6];
    const float* W1r = (const float*)d_in[7];
    const float* W0o = (const float*)d_in[8];
    const float* b0o = (const float*)d_in[9];
    const float* W1o = (const float*)d_in[10];

    const int tokens = in_sizes[0] / 128;        // 65536
    float* out0 = (float*)d_out;
    float* out1 = out0 + (size_t)tokens * 128;

    hipLaunchKernelGGL(etp_kernel, dim3(tokens / TOK), dim3(256), 0, stream,
                       z0, z1, W0l, b0l, W0r, b0r, W1l, W1r, W0o, b0o, W1o,
                       out0, out1);
}